// Round 9
// baseline (269.635 us; speedup 1.0000x reference)
//
#include <hip/hip_runtime.h>
#include <hip/hip_bf16.h>

// Problem constants: B=4, C=512, H=W=64 -> N=4096, CK=64
#define NB 4
#define CC 512
#define NN 4096
#define CKK 64

typedef _Float16 f16x4 __attribute__((ext_vector_type(4)));
typedef _Float16 f16x8 __attribute__((ext_vector_type(8)));
typedef float    f32x4 __attribute__((ext_vector_type(4)));

// ---------------------------------------------------------------------------
// async global->LDS, 16 B per lane. LDS dest is wave-uniform base + lane*16.
// ---------------------------------------------------------------------------
__device__ __forceinline__ void g2l16(const _Float16* g, _Float16* l) {
    __builtin_amdgcn_global_load_lds(
        (const __attribute__((address_space(1))) void*)g,
        (__attribute__((address_space(3))) void*)l, 16, 0, 0);
}

// Stage a 128-row x 32-col f16 tile (row stride ldg) into LDS [128][32] unpadded.
__device__ __forceinline__ void stage_tile(const _Float16* __restrict__ g, int ldg,
                                           _Float16* lds, int lane, int wave) {
    #pragma unroll
    for (int r = 0; r < 2; r++) {
        int q = r * 4 + wave;
        int row = q * 16 + (lane >> 2);
        int col = (lane & 3) * 8;
        g2l16(g + (size_t)row * ldg + col, lds + q * 512 + lane * 8);
    }
}

// ---------------------------------------------------------------------------
// K0: pack Wf/Wg/Wh -> Wall[640][512] f16, biases -> Ball[640] fp32.
// ---------------------------------------------------------------------------
__launch_bounds__(256)
__global__ void prep_w(const float* __restrict__ Wf, const float* __restrict__ bf_,
                       const float* __restrict__ Wg, const float* __restrict__ bg_,
                       const float* __restrict__ Wh, const float* __restrict__ bh_,
                       _Float16* __restrict__ Wall, float* __restrict__ Ball) {
    const int C = CC;
    int o = blockIdx.x;   // 0..639
    int t = threadIdx.x;  // 256
    const float* src;
    if (o < 64)       src = Wf + (size_t)o * C;
    else if (o < 128) src = Wg + (size_t)(o - 64) * C;
    else              src = Wh + (size_t)(o - 128) * C;
    Wall[(size_t)o * C + t]       = (_Float16)src[t];
    Wall[(size_t)o * C + 256 + t] = (_Float16)src[256 + t];
    if (t == 0)
        Ball[o] = (o < 64) ? bf_[o] : (o < 128 ? bg_[o - 64] : bh_[o - 128]);
}

// ---------------------------------------------------------------------------
// K1: projections. Y[o][n] = sum_c Wall[o][c]*x[c][n] + Ball[o]
// A = Wall (K-contig, async staged). B = x read DIRECTLY as fp32 (coalesced
// float4), cvt in VGPRs, staged to LDS Bs[k][n] with XOR bank swizzle:
// physical_col = col ^ ((k>>3)*32). Fragment reads (k = quad*8+j) then land
// quads on different bank halves -> 2-way aliasing (free, m136).
// Outputs routed: o<64 -> Ft[n][64], o<128 -> Gt[n][64], else Hx[o-128][n].
// ---------------------------------------------------------------------------
__launch_bounds__(256)
__global__ void proj_mfma(const float* __restrict__ x, const _Float16* __restrict__ Wall,
                          const float* __restrict__ Ball,
                          _Float16* __restrict__ Ft, _Float16* __restrict__ Gt,
                          _Float16* __restrict__ Hx) {
    const int N = NN, C = CC;
    int n0 = blockIdx.x * 128;
    int o0 = blockIdx.y * 128;
    int b  = blockIdx.z;
    const _Float16* Arow = Wall + (size_t)o0 * C;
    const float* xb = x + (size_t)b * C * N;
    __shared__ _Float16 As[128 * 32];   // [o][k]
    __shared__ _Float16 Bs[32 * 128];   // [k][n^swz]
    int tid = threadIdx.x, lane = tid & 63, wave = tid >> 6;
    int wm = wave & 1, wn = wave >> 1, lrow = lane & 15, quad = lane >> 4;
    int seg = tid & 31;   // 4-float column segment
    int krow = tid >> 5;  // 0..7
    f32x4 acc[4][4] = {};
    for (int kc = 0; kc < C; kc += 32) {
        __syncthreads();
        stage_tile(Arow + kc, C, As, lane, wave);
        #pragma unroll
        for (int r = 0; r < 4; r++) {
            int k = krow + 8 * r;
            float4 v = *(const float4*)(xb + (size_t)(kc + k) * N + n0 + seg * 4);
            f16x4 h = { (_Float16)v.x, (_Float16)v.y, (_Float16)v.z, (_Float16)v.w };
            int sb = (seg * 4) ^ ((k >> 3) * 32);
            *(f16x4*)(Bs + k * 128 + sb) = h;
        }
        __syncthreads();
        f16x8 af[4], bfr[4];
        #pragma unroll
        for (int mi = 0; mi < 4; mi++)
            af[mi] = *(const f16x8*)(As + (wm * 64 + mi * 16 + lrow) * 32 + quad * 8);
        #pragma unroll
        for (int ni = 0; ni < 4; ni++) {
            int col = (wn * 64 + ni * 16 + lrow) ^ (quad * 32);
            #pragma unroll
            for (int j = 0; j < 8; j++)
                bfr[ni][j] = Bs[(quad * 8 + j) * 128 + col];
        }
        #pragma unroll
        for (int mi = 0; mi < 4; mi++)
            #pragma unroll
            for (int ni = 0; ni < 4; ni++)
                acc[mi][ni] = __builtin_amdgcn_mfma_f32_16x16x32_f16(af[mi], bfr[ni], acc[mi][ni], 0, 0, 0);
    }
    float bias_r[4][4];
    #pragma unroll
    for (int mi = 0; mi < 4; mi++)
        #pragma unroll
        for (int r = 0; r < 4; r++)
            bias_r[mi][r] = Ball[o0 + wm * 64 + mi * 16 + quad * 4 + r];
    _Float16* Ftb = Ft + (size_t)b * NN * CKK;
    _Float16* Gtb = Gt + (size_t)b * NN * CKK;
    _Float16* Hxb = Hx + (size_t)b * CC * N;
    #pragma unroll
    for (int mi = 0; mi < 4; mi++)
        #pragma unroll
        for (int ni = 0; ni < 4; ni++)
            #pragma unroll
            for (int r = 0; r < 4; r++) {
                int o = o0 + wm * 64 + mi * 16 + quad * 4 + r;
                int n = n0 + wn * 64 + ni * 16 + lrow;
                _Float16 v = (_Float16)(acc[mi][ni][r] + bias_r[mi][r]);
                if (o < 64)       Ftb[(size_t)n * CKK + o] = v;
                else if (o < 128) Gtb[(size_t)n * CKK + (o - 64)] = v;
                else              Hxb[(size_t)(o - 128) * N + n] = v;
            }
}

// ---------------------------------------------------------------------------
// K2: energy fused. S = Ft_tile . Gt_tile^T (K=64). Per-tile row max Mt via
// in-register + LDS reduce; P' = exp(s16 - Mt) f16, staged through LDS and
// stored COALESCED (f16x8, 256 B/row runs); Lpart = sum of stored P' values.
// ---------------------------------------------------------------------------
#define PST_LD 136   // Pst row stride (f16): 16B-aligned rows, quad-offset banks
__launch_bounds__(256)
__global__ void energy_fused(const _Float16* __restrict__ Ft, const _Float16* __restrict__ Gt,
                             _Float16* __restrict__ P, float* __restrict__ Mpart,
                             float* __restrict__ Lpart, int r0, int Rstr) {
    const int N = NN;
    int b = blockIdx.z;
    const _Float16* Arow = Ft + (size_t)b * N * CKK + (size_t)(r0 + blockIdx.y * 128) * CKK;
    const _Float16* Brow = Gt + (size_t)b * N * CKK + (size_t)(blockIdx.x * 128) * CKK;
    _Float16* Pb = P + (size_t)b * Rstr * N + (size_t)blockIdx.y * 128 * N + blockIdx.x * 128;
    __shared__ _Float16 As[128 * 32];
    __shared__ _Float16 Bs[128 * 32];
    __shared__ _Float16 Pst[128 * PST_LD];  // 34 KB staging for coalesced P store
    __shared__ float Sred[640];  // [0..255] M halves | [256..511] L halves | [512..639] Mt
    int tid = threadIdx.x, lane = tid & 63, wave = tid >> 6;
    int wm = wave & 1, wn = wave >> 1, lrow = lane & 15, quad = lane >> 4;
    f32x4 acc[4][4] = {};
    #pragma unroll
    for (int kc = 0; kc < CKK; kc += 32) {
        __syncthreads();
        stage_tile(Arow + kc, CKK, As, lane, wave);
        stage_tile(Brow + kc, CKK, Bs, lane, wave);
        __syncthreads();
        f16x8 af[4], bf[4];
        #pragma unroll
        for (int mi = 0; mi < 4; mi++)
            af[mi] = *(const f16x8*)(As + (wm * 64 + mi * 16 + lrow) * 32 + quad * 8);
        #pragma unroll
        for (int ni = 0; ni < 4; ni++)
            bf[ni] = *(const f16x8*)(Bs + (wn * 64 + ni * 16 + lrow) * 32 + quad * 8);
        #pragma unroll
        for (int mi = 0; mi < 4; mi++)
            #pragma unroll
            for (int ni = 0; ni < 4; ni++)
                acc[mi][ni] = __builtin_amdgcn_mfma_f32_16x16x32_f16(af[mi], bf[ni], acc[mi][ni], 0, 0, 0);
    }
    // row max over this wave's 64-col half
    float mloc[16];
    #pragma unroll
    for (int mi = 0; mi < 4; mi++)
        #pragma unroll
        for (int r = 0; r < 4; r++) {
            float v = acc[mi][0][r];
            #pragma unroll
            for (int ni = 1; ni < 4; ni++) v = fmaxf(v, acc[mi][ni][r]);
            mloc[mi * 4 + r] = v;
        }
    #pragma unroll
    for (int off = 1; off < 16; off <<= 1)
        #pragma unroll
        for (int s = 0; s < 16; s++)
            mloc[s] = fmaxf(mloc[s], __shfl_xor(mloc[s], off));
    {   // lane with lrow==s publishes slot s
        float v = mloc[0];
        #pragma unroll
        for (int s = 1; s < 16; s++) v = (lrow == s) ? mloc[s] : v;
        int row = wm * 64 + (lrow >> 2) * 16 + quad * 4 + (lrow & 3);
        Sred[wn * 128 + row] = v;
    }
    __syncthreads();
    if (tid < 128) Sred[512 + tid] = fmaxf(Sred[tid], Sred[128 + tid]);
    __syncthreads();
    // P' = exp(s16 - Mt) into LDS staging; Lpart sums the f16-rounded values
    float lloc[16];
    #pragma unroll
    for (int mi = 0; mi < 4; mi++)
        #pragma unroll
        for (int r = 0; r < 4; r++) {
            int row = wm * 64 + mi * 16 + quad * 4 + r;
            float m = Sred[512 + row];
            float s = 0.f;
            #pragma unroll
            for (int ni = 0; ni < 4; ni++) {
                int j = wn * 64 + ni * 16 + lrow;
                float s16 = (float)(_Float16)acc[mi][ni][r];
                _Float16 p16 = (_Float16)__expf(s16 - m);
                Pst[row * PST_LD + j] = p16;
                s += (float)p16;
            }
            lloc[mi * 4 + r] = s;
        }
    #pragma unroll
    for (int off = 1; off < 16; off <<= 1)
        #pragma unroll
        for (int s = 0; s < 16; s++)
            lloc[s] += __shfl_xor(lloc[s], off);
    {
        float v = lloc[0];
        #pragma unroll
        for (int s = 1; s < 16; s++) v = (lrow == s) ? lloc[s] : v;
        int row = wm * 64 + (lrow >> 2) * 16 + quad * 4 + (lrow & 3);
        Sred[256 + wn * 128 + row] = v;
    }
    __syncthreads();
    if (tid < 128) {
        size_t sidx = ((size_t)b * 32 + blockIdx.x) * Rstr + blockIdx.y * 128 + tid;
        Mpart[sidx] = Sred[512 + tid];
        Lpart[sidx] = Sred[256 + tid] + Sred[256 + 128 + tid];
    }
    // coalesced P store: each row emitted as 16 f16x8 segments (256 B runs)
    int col16 = tid & 15, rowb = tid >> 4;
    #pragma unroll
    for (int s = 0; s < 8; s++) {
        int row = rowb + s * 16;
        f16x8 v = *(const f16x8*)(Pst + row * PST_LD + col16 * 8);
        *(f16x8*)(Pb + (size_t)row * N + col16 * 8) = v;
    }
}

// ---------------------------------------------------------------------------
// K4: out MFMA. O[c][i] = sum_j Hx[c][j] * (P'[i][j] * cfac[i][jt])
// Preamble computes cfac = exp(Mt - m_row)/l_row for this block's 128 rows
// directly from Mpart/Lpart. cfac applied as packed f16 muls on B fragments.
// grid: i-tile FASTEST — the 4 c-tile blocks sharing a P i-tile have IDs
// differing by 32 (=0 mod 8) -> same XCD -> P L2-shared.
// epilogue: out = gamma*O + x (fp32)
// ---------------------------------------------------------------------------
__launch_bounds__(256)
__global__ void out_mfma(const _Float16* __restrict__ Hx, const _Float16* __restrict__ P,
                         const float* __restrict__ Mpart, const float* __restrict__ Lpart,
                         const float* __restrict__ x, const float* __restrict__ gamma,
                         float* __restrict__ out, int r0, int Rstr) {
    const int N = NN, C = CC;
    int b = blockIdx.z;
    int i0l = blockIdx.x * 128;
    int c0  = blockIdx.y * 128;
    const _Float16* Arow = Hx + (size_t)b * C * N + (size_t)c0 * N;
    const _Float16* Brow = P  + (size_t)b * Rstr * N + (size_t)i0l * N;
    __shared__ _Float16 As[128 * 32];
    __shared__ _Float16 Bs[128 * 32];
    __shared__ _Float16 Cf[32 * 128];   // [jt][i_local]
    int tid = threadIdx.x, lane = tid & 63, wave = tid >> 6;
    int wm = wave & 1, wn = wave >> 1, lrow = lane & 15, quad = lane >> 4;
    // --- preamble: fold combine_stats. Threads 0..127 each own one row. ---
    if (tid < 128) {
        const float* mp = Mpart + (size_t)b * 32 * Rstr + i0l + tid;
        const float* lp = Lpart + (size_t)b * 32 * Rstr + i0l + tid;
        float mv[32];
        float m = -1e30f;
        #pragma unroll
        for (int jt = 0; jt < 32; jt++) { mv[jt] = mp[(size_t)jt * Rstr]; m = fmaxf(m, mv[jt]); }
        float l = 0.f;
        #pragma unroll
        for (int jt = 0; jt < 32; jt++) {
            float e = __expf(mv[jt] - m);
            mv[jt] = e;
            l += lp[(size_t)jt * Rstr] * e;
        }
        float linv = 1.0f / l;
        #pragma unroll
        for (int jt = 0; jt < 32; jt++)
            Cf[jt * 128 + tid] = (_Float16)(mv[jt] * linv);
    }
    __syncthreads();
    f32x4 acc[4][4] = {};
    for (int jt = 0; jt < 32; jt++) {
        _Float16 cfv[4];
        #pragma unroll
        for (int ni = 0; ni < 4; ni++)
            cfv[ni] = Cf[jt * 128 + wn * 64 + ni * 16 + lrow];
        #pragma unroll
        for (int kk = 0; kk < 4; kk++) {
            int kc = jt * 128 + kk * 32;
            __syncthreads();
            stage_tile(Arow + kc, N, As, lane, wave);
            stage_tile(Brow + kc, N, Bs, lane, wave);
            __syncthreads();
            f16x8 af[4], bf[4];
            #pragma unroll
            for (int mi = 0; mi < 4; mi++)
                af[mi] = *(const f16x8*)(As + (wm * 64 + mi * 16 + lrow) * 32 + quad * 8);
            #pragma unroll
            for (int ni = 0; ni < 4; ni++) {
                bf[ni] = *(const f16x8*)(Bs + (wn * 64 + ni * 16 + lrow) * 32 + quad * 8);
                #pragma unroll
                for (int j = 0; j < 8; j++) bf[ni][j] *= cfv[ni];
            }
            #pragma unroll
            for (int mi = 0; mi < 4; mi++)
                #pragma unroll
                for (int ni = 0; ni < 4; ni++)
                    acc[mi][ni] = __builtin_amdgcn_mfma_f32_16x16x32_f16(af[mi], bf[ni], acc[mi][ni], 0, 0, 0);
        }
    }
    float gv = gamma[0];
    const float* xb = x + (size_t)b * C * N;
    float* ob = out + (size_t)b * C * N;
    int ig0 = r0 + i0l;
    #pragma unroll
    for (int mi = 0; mi < 4; mi++)
        #pragma unroll
        for (int ni = 0; ni < 4; ni++)
            #pragma unroll
            for (int r = 0; r < 4; r++) {
                int c = c0 + wm * 64 + mi * 16 + quad * 4 + r;
                int i = ig0 + wn * 64 + ni * 16 + lrow;
                ob[(size_t)c * N + i] = gv * acc[mi][ni][r] + xb[(size_t)c * N + i];
            }
}

extern "C" void kernel_launch(void* const* d_in, const int* in_sizes, int n_in,
                              void* d_out, int out_size, void* d_ws, size_t ws_size,
                              hipStream_t stream) {
    const float* x     = (const float*)d_in[0];
    const float* Wf    = (const float*)d_in[1];
    const float* bf    = (const float*)d_in[2];
    const float* Wg    = (const float*)d_in[3];
    const float* bg    = (const float*)d_in[4];
    const float* Wh    = (const float*)d_in[5];
    const float* bh    = (const float*)d_in[6];
    const float* gamma = (const float*)d_in[7];
    float* out = (float*)d_out;

    const int B = NB, C = CC, N = NN;

    // Workspace layout (bytes):
    //   Wall [640][512] f16    @ 0        (640 KiB)
    //   Ball [640]      fp32   @ 768 KiB
    //   Ft   [B][N][64] f16    @ 1 MiB    (2 MiB)
    //   Gt   [B][N][64] f16    @ 3 MiB    (2 MiB)
    //   Hx   [B][C][N]  f16    @ 5 MiB    (16 MiB)
    //   Mpart[B][32][R] f32    @ 21 MiB   (<=2 MiB)
    //   Lpart[B][32][R] f32    @ 23 MiB   (<=2 MiB)
    //   P    [B][R][N]  f16    @ 26 MiB   (chunk, auto-sized; 134 MiB at R=4096)
    char* wsb = (char*)d_ws;
    _Float16* Wall = (_Float16*)wsb;
    float*    Ball = (float*)(wsb + ((size_t)768 << 10));
    _Float16* Ft = (_Float16*)(wsb + ((size_t)1 << 20));
    _Float16* Gt = (_Float16*)(wsb + ((size_t)3 << 20));
    _Float16* Hx = (_Float16*)(wsb + ((size_t)5 << 20));
    float* Mpart = (float*)(wsb + ((size_t)21 << 20));
    float* Lpart = (float*)(wsb + ((size_t)23 << 20));
    _Float16* P  = (_Float16*)(wsb + ((size_t)26 << 20));
    size_t base = (size_t)26 << 20;
    size_t avail = (ws_size > base) ? ws_size - base : 0;
    size_t bytesPer128 = (size_t)B * N * 2 * 128;  // 4 MiB per 128 rows of P
    int R = (int)(avail / bytesPer128) * 128;
    if (R > N) R = N;
    if (R < 128) R = 128;

    prep_w<<<dim3(640), dim3(256), 0, stream>>>(Wf, bf, Wg, bg, Wh, bh, Wall, Ball);
    proj_mfma<<<dim3(N / 128, 5, B), dim3(256), 0, stream>>>(x, Wall, Ball, Ft, Gt, Hx);

    for (int r0 = 0; r0 < N; r0 += R) {
        int rows = (R < N - r0) ? R : (N - r0);
        energy_fused<<<dim3(N / 128, rows / 128, B), dim3(256), 0, stream>>>(
            Ft, Gt, P, Mpart, Lpart, r0, R);
        out_mfma<<<dim3(rows / 128, C / 128, B), dim3(256), 0, stream>>>(
            Hx, P, Mpart, Lpart, x, gamma, out, r0, R);
    }
}